// Round 1
// baseline (2330.425 us; speedup 1.0000x reference)
//
#include <hip/hip_runtime.h>
#include <math.h>

// Problem constants (from reference)
#define BATCH 256
#define T 1024
#define IN 19
#define H 128
#define BT (BATCH * T)

// Fast tanh via exp (v_exp_f32): tanh(x) = sign(x) * (1 - 2/(exp(2|x|)+1))
// Algebraically exact; only __expf/rcp rounding (~1e-7) differs from tanhf.
__device__ __forceinline__ float fast_tanh(float x) {
    float ax = fabsf(x);
    float e  = __expf(2.0f * ax);     // exp(2|x|); inf for large ax -> r = 1
    float r  = 1.0f - 2.0f / (e + 1.0f);
    return copysignf(r, x);
}

// ---------------------------------------------------------------------------
// Kernel A: pre0[bt,h] = sum_f x[bt,f]*Wih0[h,f] + bih0[h] + bhh0[h]
// One thread per output element. x row broadcast across the 128 h-lanes (L1),
// W rows (76 B each) L1-resident. Memory-bound on the 128 MB write.
// ---------------------------------------------------------------------------
__global__ void pre0_kernel(const float* __restrict__ x,
                            const float* __restrict__ Wih0,
                            const float* __restrict__ bih0,
                            const float* __restrict__ bhh0,
                            float* __restrict__ pre0) {
    int idx = blockIdx.x * blockDim.x + threadIdx.x;   // over BT*H
    if (idx >= BT * H) return;
    int h  = idx & (H - 1);
    int bt = idx >> 7;
    const float* xr = x + (size_t)bt * IN;
    const float* wr = Wih0 + (size_t)h * IN;
    float acc = bih0[h] + bhh0[h];
#pragma unroll
    for (int f = 0; f < IN; ++f) acc += xr[f] * wr[f];
    pre0[idx] = acc;
}

// ---------------------------------------------------------------------------
// Kernels B/D: recurrent layer, IN-PLACE: buf holds pre[b,t,h] on entry,
// h_out[b,t,h] on exit. One block per batch row, thread h computes hidden
// unit h. W row lives in 128 VGPRs (persistent across all 1024 steps);
// h_{t-1} is broadcast from LDS (float4 reads). One barrier per step.
// ---------------------------------------------------------------------------
__global__ __launch_bounds__(128, 1)
void rnn_recur_kernel(float* __restrict__ buf,          // [BATCH,T,H] in/out
                      const float* __restrict__ Whh) {  // [H,H]
    const int b = blockIdx.x;    // batch row
    const int h = threadIdx.x;   // hidden unit

    __shared__ __align__(16) float hs[2][H];

    // Load my W row into registers (512 B, once per 1024 steps)
    float w[H];
#pragma unroll
    for (int k = 0; k < H; k += 4) {
        float4 v = *(const float4*)&Whh[(size_t)h * H + k];
        w[k] = v.x; w[k + 1] = v.y; w[k + 2] = v.z; w[k + 3] = v.w;
    }

    hs[0][h] = 0.0f;   // h_{-1} = 0
    __syncthreads();

    float* row = buf + (size_t)b * T * H + h;

    float pre_cur = row[0];
    int cur = 0;
    for (int t = 0; t < T; ++t) {
        // Prefetch next timestep's pre (off the critical path)
        float pre_nxt = (t + 1 < T) ? row[(size_t)(t + 1) * H] : 0.0f;

        float a0 = 0.f, a1 = 0.f, a2 = 0.f, a3 = 0.f;
#pragma unroll
        for (int k = 0; k < H; k += 4) {
            float4 hv = *(const float4*)&hs[cur][k];   // broadcast read
            a0 += w[k]     * hv.x;
            a1 += w[k + 1] * hv.y;
            a2 += w[k + 2] * hv.z;
            a3 += w[k + 3] * hv.w;
        }
        float hnew = fast_tanh(pre_cur + ((a0 + a1) + (a2 + a3)));

        row[(size_t)t * H] = hnew;      // coalesced 512 B store per block
        hs[cur ^ 1][h] = hnew;
        __syncthreads();
        cur ^= 1;
        pre_cur = pre_nxt;
    }
}

// ---------------------------------------------------------------------------
// Kernel C: pre1[bt,h] = sum_k out1[bt,k]*Wih1[h,k] + bih1[h] + bhh1[h]
// 4x4 register-tiled: each thread computes 4 bt-rows x 4 h-cols, so each
// loaded float4 feeds 16 FMAs. Block = 256 threads = 32 bt-rows x 128 h.
// ---------------------------------------------------------------------------
__global__ __launch_bounds__(256)
void proj1_kernel(const float* __restrict__ out1,
                  const float* __restrict__ Wih1,
                  const float* __restrict__ bih1,
                  const float* __restrict__ bhh1,
                  float* __restrict__ pre1) {
    const int tid = threadIdx.x;
    const int hq  = tid & 31;          // 0..31 -> h0 = hq*4
    const int btq = tid >> 5;          // 0..7  -> 4 bt rows each
    const int h0  = hq * 4;
    const int bt0 = blockIdx.x * 32 + btq * 4;

    const float* o0 = out1 + (size_t)bt0 * H;
    const float* w0 = Wih1 + (size_t)h0 * H;

    float acc[4][4] = {};
#pragma unroll 4
    for (int k = 0; k < H; k += 4) {
        float4 w[4], o[4];
#pragma unroll
        for (int i = 0; i < 4; ++i) w[i] = *(const float4*)&w0[(size_t)i * H + k];
#pragma unroll
        for (int j = 0; j < 4; ++j) o[j] = *(const float4*)&o0[(size_t)j * H + k];
#pragma unroll
        for (int j = 0; j < 4; ++j)
#pragma unroll
            for (int i = 0; i < 4; ++i)
                acc[j][i] += o[j].x * w[i].x + o[j].y * w[i].y +
                             o[j].z * w[i].z + o[j].w * w[i].w;
    }

    float4 bi = *(const float4*)&bih1[h0];
    float4 bh = *(const float4*)&bhh1[h0];
    float bs0 = bi.x + bh.x, bs1 = bi.y + bh.y, bs2 = bi.z + bh.z, bs3 = bi.w + bh.w;

#pragma unroll
    for (int j = 0; j < 4; ++j) {
        float4 r;
        r.x = acc[j][0] + bs0;
        r.y = acc[j][1] + bs1;
        r.z = acc[j][2] + bs2;
        r.w = acc[j][3] + bs3;
        *(float4*)&pre1[(size_t)(bt0 + j) * H + h0] = r;
    }
}

// ---------------------------------------------------------------------------
// Launch: A (x -> ws=pre0), B (ws in-place: pre0 -> out1),
//         C (ws -> d_out=pre1), D (d_out in-place: pre1 -> out2)
// ws usage: exactly BT*H*4 = 128 MiB (single buffer, reused in place).
// ---------------------------------------------------------------------------
extern "C" void kernel_launch(void* const* d_in, const int* in_sizes, int n_in,
                              void* d_out, int out_size, void* d_ws, size_t ws_size,
                              hipStream_t stream) {
    const float* x     = (const float*)d_in[0];
    const float* W_ih0 = (const float*)d_in[1];
    const float* W_hh0 = (const float*)d_in[2];
    const float* b_ih0 = (const float*)d_in[3];
    const float* b_hh0 = (const float*)d_in[4];
    const float* W_ih1 = (const float*)d_in[5];
    const float* W_hh1 = (const float*)d_in[6];
    const float* b_ih1 = (const float*)d_in[7];
    const float* b_hh1 = (const float*)d_in[8];

    float* ws  = (float*)d_ws;    // pre0 / out1 buffer, 128 MiB
    float* out = (float*)d_out;   // pre1 / out2 buffer, 128 MiB

    // A: input projection for layer 0
    {
        int total = BT * H;
        int threads = 256;
        int blocks = (total + threads - 1) / threads;
        pre0_kernel<<<blocks, threads, 0, stream>>>(x, W_ih0, b_ih0, b_hh0, ws);
    }
    // B: layer-0 recurrence (in place on ws)
    rnn_recur_kernel<<<BATCH, H, 0, stream>>>(ws, W_hh0);
    // C: input projection for layer 1 (reads ws=out1, writes d_out=pre1)
    proj1_kernel<<<BT / 32, 256, 0, stream>>>(ws, W_ih1, b_ih1, b_hh1, out);
    // D: layer-1 recurrence (in place on d_out)
    rnn_recur_kernel<<<BATCH, H, 0, stream>>>(out, W_hh1);
}

// Round 2
// 1943.660 us; speedup vs baseline: 1.1990x; 1.1990x over previous
//
#include <hip/hip_runtime.h>
#include <math.h>

#define BATCH 256
#define T 1024
#define IN 19
#define H 128

// tanh via v_exp_f32: tanh(x) = sign(x)*(1 - 2/(exp(2|x|)+1)); exact up to ~1e-7.
__device__ __forceinline__ float fast_tanh(float x) {
    float ax = fabsf(x);
    float e  = __expf(2.0f * ax);
    float r  = 1.0f - 2.0f / (e + 1.0f);
    return copysignf(r, x);
}

// ---------------------------------------------------------------------------
// Kernel A: pre0[bt,h] = x[bt,:].Wih0[h,:] + bih0[h] + bhh0[h]  (float4 store)
// ---------------------------------------------------------------------------
__global__ void pre0_kernel(const float* __restrict__ x,
                            const float* __restrict__ Wih0,
                            const float* __restrict__ bih0,
                            const float* __restrict__ bhh0,
                            float* __restrict__ pre0) {
    int idx = blockIdx.x * blockDim.x + threadIdx.x;   // over BT*H/4
    int h4 = (idx & 31) * 4;
    int bt = idx >> 5;
    const float* xr = x + (size_t)bt * IN;
    float xv[IN];
#pragma unroll
    for (int f = 0; f < IN; ++f) xv[f] = xr[f];
    float4 r;
    float* rp = &r.x;
#pragma unroll
    for (int i = 0; i < 4; ++i) {
        int h = h4 + i;
        const float* wr = Wih0 + (size_t)h * IN;
        float acc = bih0[h] + bhh0[h];
#pragma unroll
        for (int f = 0; f < IN; ++f) acc = fmaf(xv[f], wr[f], acc);
        rp[i] = acc;
    }
    *(float4*)&pre0[(size_t)bt * H + h4] = r;
}

// ---------------------------------------------------------------------------
// Fused 2-layer recurrence. 1 block per batch row, 256 threads.
//   G0 (tid<128), unit h: interval k computes
//       h0_k    = tanh(pre0_k + Whh0[h].h0_{k-1})        (serial cycle, lag 0)
//       B_{k-1} = Wih1[h].h0_{k-1}                        (feed-forward, lag 1)
//     -- both dots share ONE LDS read of h0_{k-1}.
//   G1 (tid>=128), unit h: interval k computes (lag 2)
//       h1_{k-2} = tanh(B_{k-2} + b1 + Whh1[h].h1_{k-3})
//   Global I/O is burst-8 (pre0 loads double-buffered, h1 stores buffered) so
//   only 1-in-8 barriers pays the __syncthreads vmcnt(0) drain.
// Intervals k = 0 .. T+1 (1026), one barrier each.
// ---------------------------------------------------------------------------
__global__ __launch_bounds__(256, 1)
void fused_rnn(const float* __restrict__ pre0,   // [B,T,H]
               const float* __restrict__ Whh0,   // [H,H]
               const float* __restrict__ Wih1,   // [H,H]
               const float* __restrict__ Whh1,   // [H,H]
               const float* __restrict__ b_ih1,
               const float* __restrict__ b_hh1,
               float* __restrict__ out) {        // [B,T,H]
    const int b   = blockIdx.x;
    const int tid = threadIdx.x;
    const bool g0 = tid < H;
    const int h   = tid & (H - 1);

    __shared__ __align__(16) float h0ring[4][H];
    __shared__ __align__(16) float h1ring[4][H];
    __shared__ __align__(16) float Bring[4][H];

    // Weight rows in registers (persistent across all 1024 steps).
    float wA[H];   // g0: Whh0 row h ; g1: Whh1 row h
    float wB[H];   // g0: Wih1 row h ; g1: unused
    {
        const float* ra = g0 ? &Whh0[(size_t)h * H] : &Whh1[(size_t)h * H];
#pragma unroll
        for (int c = 0; c < H; c += 4) {
            float4 v = *(const float4*)&ra[c];
            wA[c] = v.x; wA[c + 1] = v.y; wA[c + 2] = v.z; wA[c + 3] = v.w;
        }
        if (g0) {
            const float* rb = &Wih1[(size_t)h * H];
#pragma unroll
            for (int c = 0; c < H; c += 4) {
                float4 v = *(const float4*)&rb[c];
                wB[c] = v.x; wB[c + 1] = v.y; wB[c + 2] = v.z; wB[c + 3] = v.w;
            }
        }
    }

    const float bias1 = g0 ? 0.0f : (b_ih1[h] + b_hh1[h]);

    const float* prow = pre0 + (size_t)b * T * H + h;
    float*       orow = out  + (size_t)b * T * H + h;
    float cur[8], nxt[8], sbuf[8];
    if (g0) {
#pragma unroll
        for (int i = 0; i < 8; ++i) cur[i] = prow[(size_t)i * H];
#pragma unroll
        for (int i = 0; i < 8; ++i) nxt[i] = prow[(size_t)(8 + i) * H];
    }

    // h0_{-1} = 0, h1_{-1} = 0 live in ring slot 3.
    if (g0) h0ring[3][h] = 0.0f;
    else    h1ring[3][h] = 0.0f;
    __syncthreads();

    auto g1_step = [&](int k) {
        const int t = k - 2;
        const float* hp = h1ring[(k - 3) & 3];
        float aC = 0.f;
#pragma unroll
        for (int c = 0; c < H; c += 4) {
            float4 v = *(const float4*)&hp[c];
            aC = fmaf(wA[c],     v.x, aC);
            aC = fmaf(wA[c + 1], v.y, aC);
            aC = fmaf(wA[c + 2], v.z, aC);
            aC = fmaf(wA[c + 3], v.w, aC);
        }
        float h1v = fast_tanh(bias1 + Bring[t & 3][h] + aC);
        h1ring[t & 3][h] = h1v;
        sbuf[t & 7] = h1v;
        if ((t & 7) == 7) {
#pragma unroll
            for (int i = 0; i < 8; ++i) orow[(size_t)(t - 7 + i) * H] = sbuf[i];
        }
    };

    for (int ko = 0; ko < T; ko += 8) {
#pragma unroll
        for (int j = 0; j < 8; ++j) {
            const int k = ko + j;
            if (g0) {
                const float* hp = h0ring[(k - 1) & 3];
                float a0 = 0.f, aB = 0.f;
#pragma unroll
                for (int c = 0; c < H; c += 4) {
                    float4 v = *(const float4*)&hp[c];
                    a0 = fmaf(wA[c],     v.x, a0);
                    aB = fmaf(wB[c],     v.x, aB);
                    a0 = fmaf(wA[c + 1], v.y, a0);
                    aB = fmaf(wB[c + 1], v.y, aB);
                    a0 = fmaf(wA[c + 2], v.z, a0);
                    aB = fmaf(wB[c + 2], v.z, aB);
                    a0 = fmaf(wA[c + 3], v.w, a0);
                    aB = fmaf(wB[c + 3], v.w, aB);
                }
                float h0v = fast_tanh(cur[j] + a0);
                h0ring[k & 3][h] = h0v;
                if (k >= 1) Bring[(k - 1) & 3][h] = aB;
                if (j == 7) {
#pragma unroll
                    for (int i = 0; i < 8; ++i) cur[i] = nxt[i];
#pragma unroll
                    for (int i = 0; i < 8; ++i) {
                        int t2 = k + 9 + i;
                        if (t2 < T) nxt[i] = prow[(size_t)t2 * H];
                    }
                }
            } else if (k >= 2) {
                g1_step(k);
            }
            __syncthreads();
        }
    }

    // Tail interval k = T: G0 emits B_{T-1}; G1 emits h1_{T-2}.
    if (g0) {
        const float* hp = h0ring[(T - 1) & 3];
        float aB = 0.f;
#pragma unroll
        for (int c = 0; c < H; c += 4) {
            float4 v = *(const float4*)&hp[c];
            aB = fmaf(wB[c],     v.x, aB);
            aB = fmaf(wB[c + 1], v.y, aB);
            aB = fmaf(wB[c + 2], v.z, aB);
            aB = fmaf(wB[c + 3], v.w, aB);
        }
        Bring[(T - 1) & 3][h] = aB;
    } else {
        g1_step(T);
    }
    __syncthreads();
    // Tail interval k = T+1: G1 emits h1_{T-1} (final burst store of t=1016..1023).
    if (!g0) g1_step(T + 1);
}

// ---------------------------------------------------------------------------
extern "C" void kernel_launch(void* const* d_in, const int* in_sizes, int n_in,
                              void* d_out, int out_size, void* d_ws, size_t ws_size,
                              hipStream_t stream) {
    const float* x     = (const float*)d_in[0];
    const float* W_ih0 = (const float*)d_in[1];
    const float* W_hh0 = (const float*)d_in[2];
    const float* b_ih0 = (const float*)d_in[3];
    const float* b_hh0 = (const float*)d_in[4];
    const float* W_ih1 = (const float*)d_in[5];
    const float* W_hh1 = (const float*)d_in[6];
    const float* b_ih1 = (const float*)d_in[7];
    const float* b_hh1 = (const float*)d_in[8];

    float* ws  = (float*)d_ws;    // pre0, 128 MiB
    float* out = (float*)d_out;

    pre0_kernel<<<(BATCH * T * H / 4) / 256, 256, 0, stream>>>(x, W_ih0, b_ih0, b_hh0, ws);
    fused_rnn<<<BATCH, 256, 0, stream>>>(ws, W_hh0, W_ih1, W_hh1, b_ih1, b_hh1, out);
}

// Round 3
// 871.524 us; speedup vs baseline: 2.6740x; 2.2302x over previous
//
#include <hip/hip_runtime.h>
#include <math.h>

#define BATCH 256
#define T 1024
#define IN 19
#define H 128

// tanh via v_exp_f32: tanh(x)=sign(x)*(1-2/(exp(2|x|)+1)); exact to ~1e-7.
__device__ __forceinline__ float fast_tanh(float x) {
    float ax = fabsf(x);
    float e  = __expf(2.0f * ax);
    float r  = 1.0f - 2.0f / (e + 1.0f);
    return copysignf(r, x);
}

// ---------------------------------------------------------------------------
// Kernel A: pre0 = x . Wih0^T + b  -- block = 256 thr handles 64 bt-rows.
// W row (19 fl) in regs; x rows staged to LDS padded to 20 floats (80 B =
// 5x16B -> aligned float4 broadcast reads). Store-bound (~128 MiB, ~25 us).
// ---------------------------------------------------------------------------
__global__ __launch_bounds__(256)
void pre0_kernel(const float* __restrict__ x,
                 const float* __restrict__ Wih0,
                 const float* __restrict__ bih0,
                 const float* __restrict__ bhh0,
                 float* __restrict__ pre0) {
    const int tid  = threadIdx.x;
    const int h    = tid & 127;
    const int rr   = tid >> 7;            // 0/1: even/odd local row
    const int base = blockIdx.x * 64;     // 64 bt rows per block

    __shared__ __align__(16) float xs[64 * 20];

    float wr[IN];
    const float* wrow = Wih0 + (size_t)h * IN;
#pragma unroll
    for (int f = 0; f < IN; ++f) wr[f] = wrow[f];
    const float bh = bih0[h] + bhh0[h];

    // stage 64 x-rows (contiguous 64*19 floats), repacked to stride 20
    const float* xsrc = x + (size_t)base * IN;
#pragma unroll
    for (int it = 0; it < 5; ++it) {
        int idx = it * 256 + tid;
        if (idx < 64 * IN) {
            int r = (unsigned)idx / IN;   // magic-mul
            int f = idx - r * IN;
            xs[r * 20 + f] = xsrc[idx];
        }
    }
    __syncthreads();

    float* orow = pre0 + (size_t)base * H + h;
#pragma unroll
    for (int r = 0; r < 32; ++r) {
        int btl = r * 2 + rr;
        const float* xr = &xs[btl * 20];
        float4 x0 = *(const float4*)&xr[0];
        float4 x1 = *(const float4*)&xr[4];
        float4 x2 = *(const float4*)&xr[8];
        float4 x3 = *(const float4*)&xr[12];
        float4 x4 = *(const float4*)&xr[16];   // .w is pad, never used
        float acc = bh;
        acc = fmaf(x0.x, wr[0],  acc); acc = fmaf(x0.y, wr[1],  acc);
        acc = fmaf(x0.z, wr[2],  acc); acc = fmaf(x0.w, wr[3],  acc);
        acc = fmaf(x1.x, wr[4],  acc); acc = fmaf(x1.y, wr[5],  acc);
        acc = fmaf(x1.z, wr[6],  acc); acc = fmaf(x1.w, wr[7],  acc);
        acc = fmaf(x2.x, wr[8],  acc); acc = fmaf(x2.y, wr[9],  acc);
        acc = fmaf(x2.z, wr[10], acc); acc = fmaf(x2.w, wr[11], acc);
        acc = fmaf(x3.x, wr[12], acc); acc = fmaf(x3.y, wr[13], acc);
        acc = fmaf(x3.z, wr[14], acc); acc = fmaf(x3.w, wr[15], acc);
        acc = fmaf(x4.x, wr[16], acc); acc = fmaf(x4.y, wr[17], acc);
        acc = fmaf(x4.z, wr[18], acc);
        orow[(size_t)btl * H] = acc;
    }
}

// ---------------------------------------------------------------------------
// Fused 2-layer recurrence. 256 blocks (1/batch row) x 512 threads (8 waves,
// 2/SIMD). Per interval k (one barrier each):
//   S0 (tid<128, 2 waves):  h0_k = tanh(pre0_k + Whh0.h0_{k-1})
//   P  (tid 128..383, 4 w): B_{k-1} = Wih1.h0_{k-1} + bias1
//   S1 (tid 384..511, 2 w): h1_{k-2} = tanh(B_{k-2} + Whh1.h1_{k-3})
// Every dot is split across a thread PAIR (64-float k-slices, shfl_xor
// combine); S0/S1 threads cover 2 units each so thread i finalizes unit i.
// Max ~170 VGPR/thread -> no spills. Wave round-robin puts one serial wave
// (256 cyc) + one P wave (128 cyc) on each SIMD -> 384 cyc/SIMD/step.
// ---------------------------------------------------------------------------
__global__ __launch_bounds__(512, 2)
void fused_rnn(const float* __restrict__ pre0,   // [B,T,H]
               const float* __restrict__ Whh0,   // [H,H]
               const float* __restrict__ Wih1,   // [H,H]
               const float* __restrict__ Whh1,   // [H,H]
               const float* __restrict__ b_ih1,
               const float* __restrict__ b_hh1,
               float* __restrict__ out) {        // [B,T,H]
    const int b   = blockIdx.x;
    const int tid = threadIdx.x;

    __shared__ __align__(16) float h0ring[4][H];
    __shared__ __align__(16) float h1ring[4][H];
    __shared__ __align__(16) float Bring[4][H];

    const int grp = (tid < 128) ? 0 : (tid < 384 ? 1 : 2);

    float wA[64], wB[64];
    int q, unit;
    if (grp == 0) {
        q = tid & 1; int u0 = tid & ~1; unit = tid;
        const float* r0 = Whh0 + (size_t)u0 * H + 64 * q;
        const float* r1 = Whh0 + (size_t)(u0 + 1) * H + 64 * q;
#pragma unroll
        for (int c = 0; c < 64; c += 4) {
            float4 a = *(const float4*)&r0[c];
            float4 bb = *(const float4*)&r1[c];
            wA[c] = a.x; wA[c+1] = a.y; wA[c+2] = a.z; wA[c+3] = a.w;
            wB[c] = bb.x; wB[c+1] = bb.y; wB[c+2] = bb.z; wB[c+3] = bb.w;
        }
    } else if (grp == 1) {
        int v = tid - 128; q = v & 1; unit = v >> 1;
        const float* r0 = Wih1 + (size_t)unit * H + 64 * q;
#pragma unroll
        for (int c = 0; c < 64; c += 4) {
            float4 a = *(const float4*)&r0[c];
            wA[c] = a.x; wA[c+1] = a.y; wA[c+2] = a.z; wA[c+3] = a.w;
        }
    } else {
        int w = tid - 384; q = w & 1; int u0 = w & ~1; unit = w;
        const float* r0 = Whh1 + (size_t)u0 * H + 64 * q;
        const float* r1 = Whh1 + (size_t)(u0 + 1) * H + 64 * q;
#pragma unroll
        for (int c = 0; c < 64; c += 4) {
            float4 a = *(const float4*)&r0[c];
            float4 bb = *(const float4*)&r1[c];
            wA[c] = a.x; wA[c+1] = a.y; wA[c+2] = a.z; wA[c+3] = a.w;
            wB[c] = bb.x; wB[c+1] = bb.y; wB[c+2] = bb.z; wB[c+3] = bb.w;
        }
    }
    const float bias1 = (grp == 1) ? (b_ih1[unit] + b_hh1[unit]) : 0.0f;

    const float* prow = pre0 + (size_t)b * T * H + unit;   // S0
    float*       orow = out  + (size_t)b * T * H + unit;   // S1

    float preR[16];   // S0: pre0 for t = ko..ko+15 (two 8-banks)
    if (grp == 0) {
#pragma unroll
        for (int i2 = 0; i2 < 16; ++i2) preR[i2] = prow[(size_t)i2 * H];
    }
    float sbuf[8];    // S1: pending h1 outputs

    if (grp == 0) h0ring[3][unit] = 0.0f;   // h0_{-1}
    if (grp == 2) h1ring[3][unit] = 0.0f;   // h1_{-1}
    __syncthreads();

    // --- step bodies (inlined; register-array indices fold to literals) ---
    auto s0_step = [&](int k, float pcur) {
        const float* hp = &h0ring[(k - 1) & 3][64 * q];
        float a00 = 0.f, a01 = 0.f, a10 = 0.f, a11 = 0.f;
#pragma unroll
        for (int c = 0; c < 64; c += 4) {
            float4 hv = *(const float4*)&hp[c];
            a00 = fmaf(wA[c],     hv.x, a00);
            a10 = fmaf(wB[c],     hv.x, a10);
            a01 = fmaf(wA[c + 1], hv.y, a01);
            a11 = fmaf(wB[c + 1], hv.y, a11);
            a00 = fmaf(wA[c + 2], hv.z, a00);
            a10 = fmaf(wB[c + 2], hv.z, a10);
            a01 = fmaf(wA[c + 3], hv.w, a01);
            a11 = fmaf(wB[c + 3], hv.w, a11);
        }
        float sA = a00 + a01, sB = a10 + a11;
        float oA = __shfl_xor(sA, 1);
        float oB = __shfl_xor(sB, 1);
        float dot = (q == 0) ? (sA + oA) : (sB + oB);
        h0ring[k & 3][unit] = fast_tanh(pcur + dot);
    };

    auto p_step = [&](int k) {
        const float* hp = &h0ring[(k - 1) & 3][64 * q];
        float a0 = 0.f, a1 = 0.f, a2 = 0.f, a3 = 0.f;
#pragma unroll
        for (int c = 0; c < 64; c += 4) {
            float4 hv = *(const float4*)&hp[c];
            a0 = fmaf(wA[c],     hv.x, a0);
            a1 = fmaf(wA[c + 1], hv.y, a1);
            a2 = fmaf(wA[c + 2], hv.z, a2);
            a3 = fmaf(wA[c + 3], hv.w, a3);
        }
        float s = (a0 + a1) + (a2 + a3);
        s += __shfl_xor(s, 1);
        if (q == 0) Bring[(k - 1) & 3][unit] = s + bias1;
    };

    auto s1_step = [&](int k) {          // h1_t, t = k-2
        const int t = k - 2;
        const float* hp = &h1ring[(k - 3) & 3][64 * q];
        float a00 = 0.f, a01 = 0.f, a10 = 0.f, a11 = 0.f;
#pragma unroll
        for (int c = 0; c < 64; c += 4) {
            float4 hv = *(const float4*)&hp[c];
            a00 = fmaf(wA[c],     hv.x, a00);
            a10 = fmaf(wB[c],     hv.x, a10);
            a01 = fmaf(wA[c + 1], hv.y, a01);
            a11 = fmaf(wB[c + 1], hv.y, a11);
            a00 = fmaf(wA[c + 2], hv.z, a00);
            a10 = fmaf(wB[c + 2], hv.z, a10);
            a01 = fmaf(wA[c + 3], hv.w, a01);
            a11 = fmaf(wB[c + 3], hv.w, a11);
        }
        float sA = a00 + a01, sB = a10 + a11;
        float oA = __shfl_xor(sA, 1);
        float oB = __shfl_xor(sB, 1);
        float dot = (q == 0) ? (sA + oA) : (sB + oB);
        float h1v = fast_tanh(Bring[t & 3][unit] + dot);
        h1ring[t & 3][unit] = h1v;
        sbuf[t & 7] = h1v;
    };

    // --- main loop: intervals k = 0..1023, unrolled 16 ---
    for (int ko = 0; ko < T; ko += 16) {
#pragma unroll
        for (int j = 0; j < 16; ++j) {
            const int k = ko + j;
            if (grp == 0) {
                float pcur = preR[j];
                if (j == 7) {             // prefetch t = ko+16..23 into bank A
#pragma unroll
                    for (int i2 = 0; i2 < 8; ++i2) {
                        int t2 = ko + 16 + i2;
                        if (t2 < T) preR[i2] = prow[(size_t)t2 * H];
                    }
                } else if (j == 15) {     // prefetch t = ko+24..31 into bank B
#pragma unroll
                    for (int i2 = 0; i2 < 8; ++i2) {
                        int t2 = ko + 24 + i2;
                        if (t2 < T) preR[8 + i2] = prow[(size_t)t2 * H];
                    }
                }
                s0_step(k, pcur);
            } else if (grp == 1) {
                if (k >= 1) p_step(k);
            } else {
                if (k >= 2) s1_step(k);
                if (((j + 6) & 7) == 7 && k >= 9) {   // j==1 or j==9: flush
                    const int t0 = k - 9;
#pragma unroll
                    for (int i2 = 0; i2 < 8; ++i2)
                        orow[(size_t)(t0 + i2) * H] = sbuf[i2];
                }
            }
            __syncthreads();
        }
    }

    // --- tail intervals ---
    if (grp == 1) p_step(T);             // B_{1023}
    if (grp == 2) s1_step(T);            // h1_{1022}
    __syncthreads();
    if (grp == 2) {
        s1_step(T + 1);                  // h1_{1023}
#pragma unroll
        for (int i2 = 0; i2 < 8; ++i2)   // store t = 1016..1023
            orow[(size_t)(1016 + i2) * H] = sbuf[i2];
    }
}

// ---------------------------------------------------------------------------
extern "C" void kernel_launch(void* const* d_in, const int* in_sizes, int n_in,
                              void* d_out, int out_size, void* d_ws, size_t ws_size,
                              hipStream_t stream) {
    const float* x     = (const float*)d_in[0];
    const float* W_ih0 = (const float*)d_in[1];
    const float* W_hh0 = (const float*)d_in[2];
    const float* b_ih0 = (const float*)d_in[3];
    const float* b_hh0 = (const float*)d_in[4];
    const float* W_ih1 = (const float*)d_in[5];
    const float* W_hh1 = (const float*)d_in[6];
    const float* b_ih1 = (const float*)d_in[7];
    const float* b_hh1 = (const float*)d_in[8];

    float* ws  = (float*)d_ws;    // pre0, 128 MiB
    float* out = (float*)d_out;

    pre0_kernel<<<(BATCH * T) / 64, 256, 0, stream>>>(x, W_ih0, b_ih0, b_hh0, ws);
    fused_rnn<<<BATCH, 512, 0, stream>>>(ws, W_hh0, W_ih1, W_hh1, b_ih1, b_hh1, out);
}

// Round 4
// 782.095 us; speedup vs baseline: 2.9797x; 1.1143x over previous
//
#include <hip/hip_runtime.h>
#include <math.h>

#define BATCH 256
#define T 1024
#define IN 19
#define H 128

// tanh via v_exp_f32: tanh(x)=sign(x)*(1-2/(exp(2|x|)+1)); exact to ~1e-7.
__device__ __forceinline__ float fast_tanh(float x) {
    float ax = fabsf(x);
    float e  = __expf(2.0f * ax);
    float r  = 1.0f - 2.0f / (e + 1.0f);
    return copysignf(r, x);
}

// Padded LDS offset for hidden unit u: 16-float slices at stride 20.
// Slice s starts at s*20 -> banks {0,20,8,28,16,4,24,12}+chunk: conflict-free.
__device__ __forceinline__ int uoff(int u) { return (u >> 4) * 20 + (u & 15); }

// ---------------------------------------------------------------------------
// Kernel A: pre0 = x . Wih0^T + b.  Block = 256 thr, 64 bt-rows; thread owns
// 4 h-units (76 weight regs) x 8 rows -> float4 stores. Store-BW-bound.
// ---------------------------------------------------------------------------
__global__ __launch_bounds__(256)
void pre0_kernel(const float* __restrict__ x,
                 const float* __restrict__ Wih0,
                 const float* __restrict__ bih0,
                 const float* __restrict__ bhh0,
                 float* __restrict__ pre0) {
    const int tid  = threadIdx.x;
    const int h4   = (tid & 31) * 4;      // 4 h-units per thread
    const int rq   = tid >> 5;            // 0..7 row phase
    const int base = blockIdx.x * 64;

    __shared__ __align__(16) float xs[64 * 20];

    float w[4][IN];
#pragma unroll
    for (int u = 0; u < 4; ++u) {
        const float* wr = Wih0 + (size_t)(h4 + u) * IN;
#pragma unroll
        for (int f = 0; f < IN; ++f) w[u][f] = wr[f];
    }
    float bh[4];
#pragma unroll
    for (int u = 0; u < 4; ++u) bh[u] = bih0[h4 + u] + bhh0[h4 + u];

    const float* xsrc = x + (size_t)base * IN;
#pragma unroll
    for (int it = 0; it < 5; ++it) {
        int idx = it * 256 + tid;
        if (idx < 64 * IN) {
            int r = (unsigned)idx / IN;
            int f = idx - r * IN;
            xs[r * 20 + f] = xsrc[idx];
        }
    }
    __syncthreads();

#pragma unroll
    for (int i = 0; i < 8; ++i) {
        const int q = rq + 8 * i;
        const float* xr = &xs[q * 20];
        float4 x0 = *(const float4*)&xr[0];
        float4 x1 = *(const float4*)&xr[4];
        float4 x2 = *(const float4*)&xr[8];
        float4 x3 = *(const float4*)&xr[12];
        float4 x4 = *(const float4*)&xr[16];   // .w = pad
        float4 r;
        float* rp = &r.x;
#pragma unroll
        for (int u = 0; u < 4; ++u) {
            float acc = bh[u];
            acc = fmaf(x0.x, w[u][0],  acc); acc = fmaf(x0.y, w[u][1],  acc);
            acc = fmaf(x0.z, w[u][2],  acc); acc = fmaf(x0.w, w[u][3],  acc);
            acc = fmaf(x1.x, w[u][4],  acc); acc = fmaf(x1.y, w[u][5],  acc);
            acc = fmaf(x1.z, w[u][6],  acc); acc = fmaf(x1.w, w[u][7],  acc);
            acc = fmaf(x2.x, w[u][8],  acc); acc = fmaf(x2.y, w[u][9],  acc);
            acc = fmaf(x2.z, w[u][10], acc); acc = fmaf(x2.w, w[u][11], acc);
            acc = fmaf(x3.x, w[u][12], acc); acc = fmaf(x3.y, w[u][13], acc);
            acc = fmaf(x3.z, w[u][14], acc); acc = fmaf(x3.w, w[u][15], acc);
            acc = fmaf(x4.x, w[u][16], acc); acc = fmaf(x4.y, w[u][17], acc);
            acc = fmaf(x4.z, w[u][18], acc);
            rp[u] = acc;
        }
        *(float4*)&pre0[(size_t)(base + q) * H + h4] = r;
    }
}

// ---------------------------------------------------------------------------
// Fused 2-layer recurrence. 256 blocks x 512 threads (8 waves, 2/SIMD).
//   S0 (tid   0..127, 2 waves): h0_k = tanh(pre0_k + Whh0.h0_{k-1})
//   P  (tid 128..383, 4 waves): B_{k-1} = Wih1.h0_{k-1} + bias1
//   S1 (tid 384..511, 2 waves): h1_{k-2} = tanh(B_{k-2} + Whh1.h1_{k-3})
// S0/S1 thread: 8 units x 16-float slice (128 weight regs, 4 ds_read_b128,
// 128 FMA -> 32 FMA per b128). P thread: 4 units x 16 slice. Combines via
// 3-level shfl_xor butterfly (no LDS). Padded slice stride 20 -> 0 conflicts.
// SIMD layout (w%4): {S0,P},{S0,P},{P,S1},{P,S1} -> ~480 cyc issue balanced.
// Per-group loops: wave-uniform branches, all groups execute 1027 barriers.
// ---------------------------------------------------------------------------
__global__ __launch_bounds__(512, 2)
void fused_rnn(const float* __restrict__ pre0,   // [B,T,H]
               const float* __restrict__ Whh0,   // [H,H]
               const float* __restrict__ Wih1,   // [H,H]
               const float* __restrict__ Whh1,   // [H,H]
               const float* __restrict__ b_ih1,
               const float* __restrict__ b_hh1,
               float* __restrict__ out) {        // [B,T,H]
    const int b   = blockIdx.x;
    const int tid = threadIdx.x;

    __shared__ __align__(16) float h0ring[4][160];
    __shared__ __align__(16) float h1ring[4][160];
    __shared__ __align__(16) float Bring[4][H];

    if (tid < 128) {
        // =================== S0 ===================
        const int s    = tid & 7;                 // slice
        const int ub   = (tid >> 3) * 8;          // unit base
        const bool b0 = tid & 1, b1 = tid & 2, b2 = tid & 4;
        const int ufin = ub + (b0 ? 4 : 0) + (b1 ? 2 : 0) + (b2 ? 1 : 0);

        float wA[8][16];
#pragma unroll
        for (int u = 0; u < 8; ++u) {
            const float* wr = Whh0 + (size_t)(ub + u) * H + s * 16;
#pragma unroll
            for (int c = 0; c < 16; c += 4) {
                float4 v = *(const float4*)&wr[c];
                wA[u][c] = v.x; wA[u][c+1] = v.y; wA[u][c+2] = v.z; wA[u][c+3] = v.w;
            }
        }
        const float* prow = pre0 + (size_t)b * T * H + ufin;
        float preR[16];
#pragma unroll
        for (int i = 0; i < 16; ++i) preR[i] = prow[(size_t)i * H];

        h0ring[3][uoff(ufin)] = 0.0f;   // h0_{-1}
        __syncthreads();                 // init barrier

        const int so = s * 20;
        const int wo = uoff(ufin);
        for (int ko = 0; ko < T; ko += 16) {
#pragma unroll
            for (int j = 0; j < 16; ++j) {
                const int k = ko + j;
                float pcur = preR[j];
                if (j == 7) {
#pragma unroll
                    for (int i = 0; i < 8; ++i) {
                        int t2 = ko + 16 + i;
                        if (t2 < T) preR[i] = prow[(size_t)t2 * H];
                    }
                } else if (j == 15) {
#pragma unroll
                    for (int i = 0; i < 8; ++i) {
                        int t2 = ko + 24 + i;
                        if (t2 < T) preR[8 + i] = prow[(size_t)t2 * H];
                    }
                }
                const float* hp = &h0ring[(k + 3) & 3][so];
                float d0=0,d1=0,d2=0,d3=0,d4=0,d5=0,d6=0,d7=0;
#pragma unroll
                for (int c = 0; c < 16; c += 4) {
                    float4 hv = *(const float4*)&hp[c];
                    d0 = fmaf(wA[0][c],hv.x,d0); d0 = fmaf(wA[0][c+1],hv.y,d0); d0 = fmaf(wA[0][c+2],hv.z,d0); d0 = fmaf(wA[0][c+3],hv.w,d0);
                    d1 = fmaf(wA[1][c],hv.x,d1); d1 = fmaf(wA[1][c+1],hv.y,d1); d1 = fmaf(wA[1][c+2],hv.z,d1); d1 = fmaf(wA[1][c+3],hv.w,d1);
                    d2 = fmaf(wA[2][c],hv.x,d2); d2 = fmaf(wA[2][c+1],hv.y,d2); d2 = fmaf(wA[2][c+2],hv.z,d2); d2 = fmaf(wA[2][c+3],hv.w,d2);
                    d3 = fmaf(wA[3][c],hv.x,d3); d3 = fmaf(wA[3][c+1],hv.y,d3); d3 = fmaf(wA[3][c+2],hv.z,d3); d3 = fmaf(wA[3][c+3],hv.w,d3);
                    d4 = fmaf(wA[4][c],hv.x,d4); d4 = fmaf(wA[4][c+1],hv.y,d4); d4 = fmaf(wA[4][c+2],hv.z,d4); d4 = fmaf(wA[4][c+3],hv.w,d4);
                    d5 = fmaf(wA[5][c],hv.x,d5); d5 = fmaf(wA[5][c+1],hv.y,d5); d5 = fmaf(wA[5][c+2],hv.z,d5); d5 = fmaf(wA[5][c+3],hv.w,d5);
                    d6 = fmaf(wA[6][c],hv.x,d6); d6 = fmaf(wA[6][c+1],hv.y,d6); d6 = fmaf(wA[6][c+2],hv.z,d6); d6 = fmaf(wA[6][c+3],hv.w,d6);
                    d7 = fmaf(wA[7][c],hv.x,d7); d7 = fmaf(wA[7][c+1],hv.y,d7); d7 = fmaf(wA[7][c+2],hv.z,d7); d7 = fmaf(wA[7][c+3],hv.w,d7);
                }
                float e0 = (b0 ? d4 : d0) + __shfl_xor(b0 ? d0 : d4, 1);
                float e1 = (b0 ? d5 : d1) + __shfl_xor(b0 ? d1 : d5, 1);
                float e2 = (b0 ? d6 : d2) + __shfl_xor(b0 ? d2 : d6, 1);
                float e3 = (b0 ? d7 : d3) + __shfl_xor(b0 ? d3 : d7, 1);
                float g0 = (b1 ? e2 : e0) + __shfl_xor(b1 ? e0 : e2, 2);
                float g1 = (b1 ? e3 : e1) + __shfl_xor(b1 ? e1 : e3, 2);
                float f  = (b2 ? g1 : g0) + __shfl_xor(b2 ? g0 : g1, 4);
                h0ring[k & 3][wo] = fast_tanh(pcur + f);
                __syncthreads();
            }
        }
        __syncthreads();   // interval 1024
        __syncthreads();   // interval 1025
    } else if (tid < 384) {
        // =================== P ===================
        const int p  = tid - 128;
        const int s  = p & 7;
        const int ub = (p >> 3) * 4;
        const bool b0 = p & 1, b1 = p & 2, b2 = p & 4;
        const int ufin = ub + (b0 ? 2 : 0) + (b1 ? 1 : 0);

        float wP[4][16];
#pragma unroll
        for (int u = 0; u < 4; ++u) {
            const float* wr = Wih1 + (size_t)(ub + u) * H + s * 16;
#pragma unroll
            for (int c = 0; c < 16; c += 4) {
                float4 v = *(const float4*)&wr[c];
                wP[u][c] = v.x; wP[u][c+1] = v.y; wP[u][c+2] = v.z; wP[u][c+3] = v.w;
            }
        }
        const float biasP = b_ih1[ufin] + b_hh1[ufin];

        __syncthreads();   // init barrier
        __syncthreads();   // interval 0 (no work)

        const int so = s * 20;
        for (int ko = 1; ko < 1025; ko += 16) {
#pragma unroll
            for (int j = 0; j < 16; ++j) {
                const int k = ko + j;
                const float* hp = &h0ring[(k + 3) & 3][so];
                float d0=0,d1=0,d2=0,d3=0;
#pragma unroll
                for (int c = 0; c < 16; c += 4) {
                    float4 hv = *(const float4*)&hp[c];
                    d0 = fmaf(wP[0][c],hv.x,d0); d0 = fmaf(wP[0][c+1],hv.y,d0); d0 = fmaf(wP[0][c+2],hv.z,d0); d0 = fmaf(wP[0][c+3],hv.w,d0);
                    d1 = fmaf(wP[1][c],hv.x,d1); d1 = fmaf(wP[1][c+1],hv.y,d1); d1 = fmaf(wP[1][c+2],hv.z,d1); d1 = fmaf(wP[1][c+3],hv.w,d1);
                    d2 = fmaf(wP[2][c],hv.x,d2); d2 = fmaf(wP[2][c+1],hv.y,d2); d2 = fmaf(wP[2][c+2],hv.z,d2); d2 = fmaf(wP[2][c+3],hv.w,d2);
                    d3 = fmaf(wP[3][c],hv.x,d3); d3 = fmaf(wP[3][c+1],hv.y,d3); d3 = fmaf(wP[3][c+2],hv.z,d3); d3 = fmaf(wP[3][c+3],hv.w,d3);
                }
                float e0 = (b0 ? d2 : d0) + __shfl_xor(b0 ? d0 : d2, 1);
                float e1 = (b0 ? d3 : d1) + __shfl_xor(b0 ? d1 : d3, 1);
                float g  = (b1 ? e1 : e0) + __shfl_xor(b1 ? e0 : e1, 2);
                g += __shfl_xor(g, 4);
                if (!b2) Bring[(k + 3) & 3][ufin] = g + biasP;
                __syncthreads();
            }
        }
        __syncthreads();   // interval 1025
    } else {
        // =================== S1 ===================
        const int w  = tid - 384;
        const int s  = w & 7;
        const int ub = (w >> 3) * 8;
        const bool b0 = w & 1, b1 = w & 2, b2 = w & 4;
        const int ufin = ub + (b0 ? 4 : 0) + (b1 ? 2 : 0) + (b2 ? 1 : 0);

        float wA[8][16];
#pragma unroll
        for (int u = 0; u < 8; ++u) {
            const float* wr = Whh1 + (size_t)(ub + u) * H + s * 16;
#pragma unroll
            for (int c = 0; c < 16; c += 4) {
                float4 v = *(const float4*)&wr[c];
                wA[u][c] = v.x; wA[u][c+1] = v.y; wA[u][c+2] = v.z; wA[u][c+3] = v.w;
            }
        }
        float* orow = out + (size_t)b * T * H + ufin;
        float sbuf[8];

        h1ring[3][uoff(ufin)] = 0.0f;   // h1_{-1}
        __syncthreads();   // init barrier
        __syncthreads();   // interval 0
        __syncthreads();   // interval 1

        const int so = s * 20;
        const int wo = uoff(ufin);
        for (int ko = 2; ko < 1026; ko += 16) {
#pragma unroll
            for (int j = 0; j < 16; ++j) {
                const int k = ko + j;                 // t = k-2, t&7 == j&7
                const float* hp = &h1ring[(k + 1) & 3][so];
                float Bg = Bring[(k + 2) & 3][ufin];
                float d0=0,d1=0,d2=0,d3=0,d4=0,d5=0,d6=0,d7=0;
#pragma unroll
                for (int c = 0; c < 16; c += 4) {
                    float4 hv = *(const float4*)&hp[c];
                    d0 = fmaf(wA[0][c],hv.x,d0); d0 = fmaf(wA[0][c+1],hv.y,d0); d0 = fmaf(wA[0][c+2],hv.z,d0); d0 = fmaf(wA[0][c+3],hv.w,d0);
                    d1 = fmaf(wA[1][c],hv.x,d1); d1 = fmaf(wA[1][c+1],hv.y,d1); d1 = fmaf(wA[1][c+2],hv.z,d1); d1 = fmaf(wA[1][c+3],hv.w,d1);
                    d2 = fmaf(wA[2][c],hv.x,d2); d2 = fmaf(wA[2][c+1],hv.y,d2); d2 = fmaf(wA[2][c+2],hv.z,d2); d2 = fmaf(wA[2][c+3],hv.w,d2);
                    d3 = fmaf(wA[3][c],hv.x,d3); d3 = fmaf(wA[3][c+1],hv.y,d3); d3 = fmaf(wA[3][c+2],hv.z,d3); d3 = fmaf(wA[3][c+3],hv.w,d3);
                    d4 = fmaf(wA[4][c],hv.x,d4); d4 = fmaf(wA[4][c+1],hv.y,d4); d4 = fmaf(wA[4][c+2],hv.z,d4); d4 = fmaf(wA[4][c+3],hv.w,d4);
                    d5 = fmaf(wA[5][c],hv.x,d5); d5 = fmaf(wA[5][c+1],hv.y,d5); d5 = fmaf(wA[5][c+2],hv.z,d5); d5 = fmaf(wA[5][c+3],hv.w,d5);
                    d6 = fmaf(wA[6][c],hv.x,d6); d6 = fmaf(wA[6][c+1],hv.y,d6); d6 = fmaf(wA[6][c+2],hv.z,d6); d6 = fmaf(wA[6][c+3],hv.w,d6);
                    d7 = fmaf(wA[7][c],hv.x,d7); d7 = fmaf(wA[7][c+1],hv.y,d7); d7 = fmaf(wA[7][c+2],hv.z,d7); d7 = fmaf(wA[7][c+3],hv.w,d7);
                }
                float e0 = (b0 ? d4 : d0) + __shfl_xor(b0 ? d0 : d4, 1);
                float e1 = (b0 ? d5 : d1) + __shfl_xor(b0 ? d1 : d5, 1);
                float e2 = (b0 ? d6 : d2) + __shfl_xor(b0 ? d2 : d6, 1);
                float e3 = (b0 ? d7 : d3) + __shfl_xor(b0 ? d3 : d7, 1);
                float g0 = (b1 ? e2 : e0) + __shfl_xor(b1 ? e0 : e2, 2);
                float g1 = (b1 ? e3 : e1) + __shfl_xor(b1 ? e1 : e3, 2);
                float f  = (b2 ? g1 : g0) + __shfl_xor(b2 ? g0 : g1, 4);
                float h1v = fast_tanh(Bg + f);
                h1ring[(k + 2) & 3][wo] = h1v;
                sbuf[j & 7] = h1v;
                if (j == 7 || j == 15) {       // t = ko-2+j ends an 8-burst
                    const int t0 = ko - 9 + j; // t-7
#pragma unroll
                    for (int i = 0; i < 8; ++i)
                        orow[(size_t)(t0 + i) * H] = sbuf[i];
                }
                __syncthreads();
            }
        }
        // no trailing barriers needed for S1 (last interval is 1025)
    }
}

// ---------------------------------------------------------------------------
extern "C" void kernel_launch(void* const* d_in, const int* in_sizes, int n_in,
                              void* d_out, int out_size, void* d_ws, size_t ws_size,
                              hipStream_t stream) {
    const float* x     = (const float*)d_in[0];
    const float* W_ih0 = (const float*)d_in[1];
    const float* W_hh0 = (const float*)d_in[2];
    const float* b_ih0 = (const float*)d_in[3];
    const float* b_hh0 = (const float*)d_in[4];
    const float* W_ih1 = (const float*)d_in[5];
    const float* W_hh1 = (const float*)d_in[6];
    const float* b_ih1 = (const float*)d_in[7];
    const float* b_hh1 = (const float*)d_in[8];

    float* ws  = (float*)d_ws;    // pre0, 128 MiB
    float* out = (float*)d_out;

    pre0_kernel<<<(BATCH * T) / 64, 256, 0, stream>>>(x, W_ih0, b_ih0, b_hh0, ws);
    fused_rnn<<<BATCH, 512, 0, stream>>>(ws, W_hh0, W_ih1, W_hh1, b_ih1, b_hh1, out);
}